// Round 6
// baseline (1103.662 us; speedup 1.0000x reference)
//
#include <hip/hip_runtime.h>
#include <hip/hip_bf16.h>

typedef __attribute__((ext_vector_type(8))) short s8v;
typedef __attribute__((ext_vector_type(4))) float f4v;

#define NNODES 100000
#define NEDGES 1600000
#define NFEAT 512
#define NHID 128
#define NCLS 64
#define NB1 391   // ceil(NNODES/256)
#define DBINS 512

static __device__ __forceinline__ short f2bf(float f) {
  __hip_bfloat16 h = __float2bfloat16(f);
  return __builtin_bit_cast(short, h);
}
static __device__ __forceinline__ float bflo(unsigned int u) {
  return __builtin_bit_cast(float, u << 16);
}
static __device__ __forceinline__ float bfhi(unsigned int u) {
  return __builtin_bit_cast(float, u & 0xFFFF0000u);
}

// ---- edge dtype detection: int64 => odd 32-bit words all zero ----
__global__ __launch_bounds__(1024) void detect_k(const int* __restrict__ ei, int* flag) {
  int i = blockIdx.x * blockDim.x + threadIdx.x;
  if (i < 1024 && ei[2 * i + 1] != 0) atomicOr(flag, 1); // flag=1 -> int32 data
}

__global__ __launch_bounds__(256) void hist_k(const int* __restrict__ ei,
                                              const int* __restrict__ flag,
                                              int* __restrict__ cnt) {
  bool is32 = (*flag != 0);
  int stride = gridDim.x * blockDim.x;
  for (int e = blockIdx.x * blockDim.x + threadIdx.x; e < NEDGES; e += stride) {
    int d = is32 ? ei[NEDGES + e] : ei[2 * NEDGES + 2 * e];
    atomicAdd(&cnt[d], 1);
  }
}

// ---- hierarchical exclusive scan of cnt -> rs ----
__global__ __launch_bounds__(256) void scan1_k(const int* __restrict__ cnt,
                                               int* __restrict__ rs,
                                               int* __restrict__ bsum) {
  __shared__ int sm[256];
  int t = threadIdx.x;
  int i = blockIdx.x * 256 + t;
  int v = (i < NNODES) ? cnt[i] : 0;
  sm[t] = v;
  __syncthreads();
  for (int off = 1; off < 256; off <<= 1) {
    int val = (t >= off) ? sm[t - off] : 0;
    __syncthreads();
    sm[t] += val;
    __syncthreads();
  }
  if (i < NNODES) rs[i] = sm[t] - v;
  if (t == 255) bsum[blockIdx.x] = sm[255];
}

__global__ __launch_bounds__(512) void scan2_k(int* __restrict__ bsum, int* __restrict__ rs) {
  __shared__ int sm[512];
  int t = threadIdx.x;
  int v = (t < NB1) ? bsum[t] : 0;
  sm[t] = v;
  __syncthreads();
  for (int off = 1; off < 512; off <<= 1) {
    int val = (t >= off) ? sm[t - off] : 0;
    __syncthreads();
    sm[t] += val;
    __syncthreads();
  }
  if (t < NB1) bsum[t] = sm[t] - v;
  if (t == 511) rs[NNODES] = sm[511];
}

__global__ __launch_bounds__(256) void scan3_k(const int* __restrict__ cnt,
                                               const int* __restrict__ bsum,
                                               int* __restrict__ rs,
                                               float* __restrict__ dinv) {
  int i = blockIdx.x * 256 + threadIdx.x;
  if (i < NNODES) {
    rs[i] += bsum[blockIdx.x];
    dinv[i] = rsqrtf((float)(cnt[i] + 1));
  }
}

__global__ __launch_bounds__(256) void scatter_k(const int* __restrict__ ei,
                                                 const int* __restrict__ flag,
                                                 const int* __restrict__ rs,
                                                 int* __restrict__ cursor,
                                                 int* __restrict__ csrc) {
  bool is32 = (*flag != 0);
  int stride = gridDim.x * blockDim.x;
  for (int e = blockIdx.x * blockDim.x + threadIdx.x; e < NEDGES; e += stride) {
    int s, d;
    if (is32) { s = ei[e];     d = ei[NEDGES + e]; }
    else      { s = ei[2 * e]; d = ei[2 * NEDGES + 2 * e]; }
    int pos = rs[d] + atomicAdd(&cursor[d], 1);
    csrc[pos] = s;
  }
}

// ---- degree-grouping (counting sort by degree) ----
__global__ __launch_bounds__(256) void deghist_k(const int* __restrict__ cnt,
                                                 int* __restrict__ dh) {
  int i = blockIdx.x * 256 + threadIdx.x;
  if (i < NNODES) {
    int d = cnt[i]; if (d > DBINS - 1) d = DBINS - 1;
    atomicAdd(&dh[d], 1);
  }
}
__global__ __launch_bounds__(512) void degscan_k(int* __restrict__ dh) {
  __shared__ int sm[512];
  int t = threadIdx.x;
  int v = dh[t];
  sm[t] = v;
  __syncthreads();
  for (int off = 1; off < 512; off <<= 1) {
    int val = (t >= off) ? sm[t - off] : 0;
    __syncthreads();
    sm[t] += val;
    __syncthreads();
  }
  dh[t] = sm[t] - v;
}
__global__ __launch_bounds__(256) void degorder_k(const int* __restrict__ cnt,
                                                  const int* __restrict__ dh,
                                                  int* __restrict__ dcur,
                                                  int* __restrict__ order) {
  int i = blockIdx.x * 256 + threadIdx.x;
  if (i < NNODES) {
    int d = cnt[i]; if (d > DBINS - 1) d = DBINS - 1;
    int pos = dh[d] + atomicAdd(&dcur[d], 1);
    order[pos] = i;
  }
}

// ---- weight transpose+convert ----
__global__ __launch_bounds__(256) void w1t_k(const float* __restrict__ W1, short* __restrict__ W1t) {
  int i = blockIdx.x * 256 + threadIdx.x;
  if (i < NFEAT * NHID) {
    int k = i >> 7, c = i & 127;
    W1t[(size_t)c * NFEAT + k] = f2bf(W1[i]);
  }
}
__global__ __launch_bounds__(256) void w2t_k(const float* __restrict__ W2, short* __restrict__ W2t) {
  int i = blockIdx.x * 256 + threadIdx.x;
  if (i < NHID * NCLS) {
    int k = i >> 6, c = i & 63;
    W2t[(size_t)c * NHID + k] = f2bf(W2[i]);
  }
}

// ---- fused MLP, K-split: block = 16 rows, wave w owns K-slice [w*128,(w+1)*128) ----
// gemm1 partials reduced via LDS; h1 recomputed in-register; gemm2 16-col slice/wave.
__global__ __launch_bounds__(256, 4) void mlp2_k(const float* __restrict__ x,
                                                 const short* __restrict__ W1t,
                                                 const float* __restrict__ b1,
                                                 const short* __restrict__ W2t,
                                                 const float* __restrict__ b2,
                                                 const float* __restrict__ dinv,
                                                 unsigned short* __restrict__ x0,
                                                 unsigned short* __restrict__ g0) {
  __shared__ __align__(16) float part[4][16][134]; // padded: rows shift 6 banks
  int tid = threadIdx.x, lane = tid & 63, wave = tid >> 6;
  int r = lane & 15, q = lane >> 4;
  int row0 = blockIdx.x * 16; // NNODES = 16*6250 exactly
  const float* xr = x + (size_t)(row0 + r) * NFEAT + wave * 128 + q * 8;
  const short* bp1 = W1t + (size_t)r * NFEAT + wave * 128 + q * 8;

  // all A upfront: 4 chunks x 2 float4 (32 VGPR)
  float4 A[4][2];
#pragma unroll
  for (int c = 0; c < 4; ++c) {
    A[c][0] = *reinterpret_cast<const float4*>(xr + c * 32);
    A[c][1] = *reinterpret_cast<const float4*>(xr + c * 32 + 4);
  }
  f4v acc[8];
#pragma unroll
  for (int i = 0; i < 8; ++i) acc[i] = (f4v){0.f, 0.f, 0.f, 0.f};
#pragma unroll
  for (int c = 0; c < 4; ++c) {
    s8v a;
    a[0] = f2bf(A[c][0].x); a[1] = f2bf(A[c][0].y);
    a[2] = f2bf(A[c][0].z); a[3] = f2bf(A[c][0].w);
    a[4] = f2bf(A[c][1].x); a[5] = f2bf(A[c][1].y);
    a[6] = f2bf(A[c][1].z); a[7] = f2bf(A[c][1].w);
#pragma unroll
    for (int ct = 0; ct < 8; ++ct) {
      s8v b = *reinterpret_cast<const s8v*>(bp1 + (size_t)ct * 16 * NFEAT + c * 32);
      acc[ct] = __builtin_amdgcn_mfma_f32_16x16x32_bf16(a, b, acc[ct], 0, 0, 0);
    }
  }
  // partials -> LDS (D-frag: col=lane&15, row=q*4+j); 2-way banks (free)
#pragma unroll
  for (int ct = 0; ct < 8; ++ct)
#pragma unroll
    for (int j = 0; j < 4; ++j)
      part[wave][q * 4 + j][ct * 16 + r] = acc[ct][j];
  __syncthreads();

  // recompute h1 slice for this wave's gemm2 A-frags: row r, k = c2*32 + q*8 + [0..8)
  s8v a2[4];
#pragma unroll
  for (int c2 = 0; c2 < 4; ++c2) {
    int k = c2 * 32 + q * 8;
    float hv[8];
#pragma unroll
    for (int jj = 0; jj < 8; jj += 2) {
      float sx = 0.f, sy = 0.f;
#pragma unroll
      for (int w = 0; w < 4; ++w) {
        float2 p = *reinterpret_cast<const float2*>(&part[w][r][k + jj]);
        sx += p.x; sy += p.y;
      }
      hv[jj] = sx; hv[jj + 1] = sy;
    }
    float4 bb0 = *reinterpret_cast<const float4*>(b1 + k);
    float4 bb1 = *reinterpret_cast<const float4*>(b1 + k + 4);
    hv[0] += bb0.x; hv[1] += bb0.y; hv[2] += bb0.z; hv[3] += bb0.w;
    hv[4] += bb1.x; hv[5] += bb1.y; hv[6] += bb1.z; hv[7] += bb1.w;
#pragma unroll
    for (int i = 0; i < 8; ++i) {
      float v = hv[i] > 0.f ? hv[i] : 0.f;
      a2[c2][i] = f2bf(v);
    }
  }
  // gemm2: this wave computes cols [wave*16, wave*16+16)
  const short* bp2 = W2t + (size_t)(wave * 16 + r) * NHID + q * 8;
  f4v acc2 = (f4v){0.f, 0.f, 0.f, 0.f};
#pragma unroll
  for (int c2 = 0; c2 < 4; ++c2) {
    s8v b = *reinterpret_cast<const s8v*>(bp2 + c2 * 32);
    acc2 = __builtin_amdgcn_mfma_f32_16x16x32_bf16(a2[c2], b, acc2, 0, 0, 0);
  }
  float bias2 = b2[wave * 16 + r];
  float dvv[4];
#pragma unroll
  for (int j = 0; j < 4; ++j) dvv[j] = dinv[row0 + q * 4 + j];
  __syncthreads(); // all partial reads done; reuse LDS as pack buffers

  short* pkx = (short*)&part[0][0][0]; // [16][72]
  short* pkg = pkx + 16 * 72;
#pragma unroll
  for (int j = 0; j < 4; ++j) {
    float hh = acc2[j] + bias2;
    int off = (q * 4 + j) * 72 + wave * 16 + r;
    pkx[off] = f2bf(hh);
    pkg[off] = f2bf(dvv[j] * hh);
  }
  __syncthreads();
  int sel = tid >> 7;          // wave-uniform: 0 -> x0, 1 -> g0
  int t2 = tid & 127;
  int rw = t2 >> 3, seg = t2 & 7;
  const short* src = (sel ? pkg : pkx) + rw * 72 + seg * 8;
  s8v v = *reinterpret_cast<const s8v*>(src);
  unsigned short* dst = (sel ? g0 : x0) + (size_t)(row0 + rw) * NCLS + seg * 8;
  *reinterpret_cast<s8v*>(dst) = v;
}

// ---- propagation: degree-grouped order; 4 nodes/wave, 16 lanes/node ----
__global__ __launch_bounds__(256) void prop_k(const unsigned short* __restrict__ gin,
                                              const unsigned short* __restrict__ x0,
                                              const float* __restrict__ dinv,
                                              const int* __restrict__ rs,
                                              const int* __restrict__ csrc,
                                              const int* __restrict__ order,
                                              unsigned short* __restrict__ gout,
                                              float* __restrict__ out,
                                              int last) {
  int tid = threadIdx.x;
  int lane = tid & 63;
  int r = lane & 15;
  int gbase = lane & 48;
  int pos = blockIdx.x * 16 + (tid >> 6) * 4 + (lane >> 4); // exact: 6250*16 = NNODES
  int node = order[pos];
  int b = rs[node];
  int deg = rs[node + 1] - b;

  uint2 sv = ((const uint2*)(gin + (size_t)node * NCLS))[r];
  float a0 = bflo(sv.x), a1 = bfhi(sv.x), a2 = bflo(sv.y), a3 = bfhi(sv.y);

  int m = deg;
  m = max(m, __shfl_xor(m, 16));
  m = max(m, __shfl_xor(m, 32));

  int basek = 0;
  for (; basek + 16 <= m; basek += 16) {
    int idx = NNODES;
    if (basek + r < deg) idx = csrc[b + basek + r];
#pragma unroll
    for (int j = 0; j < 16; ++j) {
      int sj = __shfl(idx, gbase + j);
      uint2 v = ((const uint2*)(gin + (size_t)sj * NCLS))[r];
      a0 += bflo(v.x); a1 += bfhi(v.x); a2 += bflo(v.y); a3 += bfhi(v.y);
    }
  }
  if (basek < m) {
    int idx = NNODES;
    if (basek + r < deg) idx = csrc[b + basek + r];
    int rem = m - basek;
    for (int j = 0; j < rem; ++j) {
      int sj = __shfl(idx, gbase + j);
      uint2 v = ((const uint2*)(gin + (size_t)sj * NCLS))[r];
      a0 += bflo(v.x); a1 += bfhi(v.x); a2 += bflo(v.y); a3 += bfhi(v.y);
    }
  }

  float dvn = dinv[node];
  uint2 xv = ((const uint2*)(x0 + (size_t)node * NCLS))[r];
  float h0 = 0.9f * (dvn * a0) + 0.1f * bflo(xv.x);
  float h1 = 0.9f * (dvn * a1) + 0.1f * bfhi(xv.x);
  float h2 = 0.9f * (dvn * a2) + 0.1f * bflo(xv.y);
  float h3 = 0.9f * (dvn * a3) + 0.1f * bfhi(xv.y);

  if (!last) {
    unsigned int p0 = (unsigned short)f2bf(dvn * h0) |
                      ((unsigned int)(unsigned short)f2bf(dvn * h1) << 16);
    unsigned int p1 = (unsigned short)f2bf(dvn * h2) |
                      ((unsigned int)(unsigned short)f2bf(dvn * h3) << 16);
    uint2 o; o.x = p0; o.y = p1;
    ((uint2*)(gout + (size_t)node * NCLS))[r] = o;
  } else {
    float mx = fmaxf(fmaxf(h0, h1), fmaxf(h2, h3));
#pragma unroll
    for (int off = 1; off < 16; off <<= 1) mx = fmaxf(mx, __shfl_xor(mx, off));
    float s = __expf(h0 - mx) + __expf(h1 - mx) + __expf(h2 - mx) + __expf(h3 - mx);
#pragma unroll
    for (int off = 1; off < 16; off <<= 1) s += __shfl_xor(s, off);
    float ls = __logf(s);
    float4 o = {h0 - mx - ls, h1 - mx - ls, h2 - mx - ls, h3 - mx - ls};
    *(float4*)(out + (size_t)node * NCLS + r * 4) = o;
  }
}

extern "C" void kernel_launch(void* const* d_in, const int* in_sizes, int n_in,
                              void* d_out, int out_size, void* d_ws, size_t ws_size,
                              hipStream_t stream) {
  const float* x  = (const float*)d_in[0];
  const int*   ei = (const int*)d_in[1];
  const float* W1 = (const float*)d_in[2];
  const float* b1 = (const float*)d_in[3];
  const float* W2 = (const float*)d_in[4];
  const float* b2 = (const float*)d_in[5];

  char* ws = (char*)d_ws;
  unsigned short* x0bf   = (unsigned short*)(ws);             // 12.8 MB
  unsigned short* gA     = (unsigned short*)(ws + 12800000);  // 12.8 MB + zero row
  unsigned short* gB     = (unsigned short*)(ws + 25600256);  // 12.8 MB + zero row
  int*            csrc   = (int*)(ws + 38400384);             // 6.4 MB
  int*            cnt    = (int*)(ws + 44800384);             // 400 KB
  int*            rs     = (int*)(ws + 45200384);             // 400.128 KB
  int*            cursor = (int*)(ws + 45600512);             // 400 KB
  float*          dinv   = (float*)(ws + 46000512);           // 400 KB
  int*            order  = (int*)(ws + 46400512);             // 400 KB
  short*          W1t    = (short*)(ws + 46800512);           // 128 KB
  short*          W2t    = (short*)(ws + 46931584);           // 16 KB
  int*            flag   = (int*)(ws + 46947968);             // 4 B (+pad)
  int*            bsum   = (int*)(ws + 46948096);             // 1.6 KB
  int*            dh     = (int*)(ws + 46949696);             // 2 KB
  int*            dcur   = (int*)(ws + 46951744);             // 2 KB

  hipMemsetAsync(ws + 44800384, 0, 1200128, stream); // cnt + rs + cursor
  hipMemsetAsync(ws + 46947968, 0, 128, stream);     // flag
  hipMemsetAsync(ws + 46949696, 0, 4096, stream);    // dh + dcur
  hipMemsetAsync((char*)gA + (size_t)NNODES * NCLS * 2, 0, 128, stream);
  hipMemsetAsync((char*)gB + (size_t)NNODES * NCLS * 2, 0, 128, stream);

  detect_k<<<1, 1024, 0, stream>>>(ei, flag);
  hist_k<<<2048, 256, 0, stream>>>(ei, flag, cnt);
  scan1_k<<<NB1, 256, 0, stream>>>(cnt, rs, bsum);
  scan2_k<<<1, 512, 0, stream>>>(bsum, rs);
  scan3_k<<<NB1, 256, 0, stream>>>(cnt, bsum, rs, dinv);
  scatter_k<<<2048, 256, 0, stream>>>(ei, flag, rs, cursor, csrc);

  deghist_k<<<NB1, 256, 0, stream>>>(cnt, dh);
  degscan_k<<<1, 512, 0, stream>>>(dh);
  degorder_k<<<NB1, 256, 0, stream>>>(cnt, dh, dcur, order);

  w1t_k<<<(NFEAT * NHID + 255) / 256, 256, 0, stream>>>(W1, W1t);
  w2t_k<<<(NHID * NCLS + 255) / 256, 256, 0, stream>>>(W2, W2t);

  mlp2_k<<<NNODES / 16, 256, 0, stream>>>(x, W1t, b1, W2t, b2, dinv, x0bf, gB);

  // g0 in gB; odd t writes gA, even t writes gB; t=10 reads gA, writes d_out (f32)
  for (int t = 1; t <= 10; ++t) {
    const unsigned short* gin = (t & 1) ? gB : gA;
    unsigned short* gout      = (t & 1) ? gA : gB;
    prop_k<<<NNODES / 16, 256, 0, stream>>>(gin, x0bf, dinv, rs, csrc, order, gout,
                                            (float*)d_out, t == 10);
  }
}

// Round 7
// 737.749 us; speedup vs baseline: 1.4960x; 1.4960x over previous
//
#include <hip/hip_runtime.h>
#include <hip/hip_bf16.h>

typedef __attribute__((ext_vector_type(8))) short s8v;
typedef __attribute__((ext_vector_type(4))) float f4v;

#define NNODES 100000
#define NEDGES 1600000
#define NFEAT 512
#define NHID 128
#define NCLS 64
#define NB1 391   // ceil(NNODES/256)

static __device__ __forceinline__ short f2bf(float f) {
  __hip_bfloat16 h = __float2bfloat16(f);
  return __builtin_bit_cast(short, h);
}
static __device__ __forceinline__ float bflo(unsigned int u) {
  return __builtin_bit_cast(float, u << 16);
}
static __device__ __forceinline__ float bfhi(unsigned int u) {
  return __builtin_bit_cast(float, u & 0xFFFF0000u);
}

// ---- edge dtype detection: int64 => odd 32-bit words all zero ----
__global__ __launch_bounds__(1024) void detect_k(const int* __restrict__ ei, int* flag) {
  int i = blockIdx.x * blockDim.x + threadIdx.x;
  if (i < 1024 && ei[2 * i + 1] != 0) atomicOr(flag, 1); // flag=1 -> int32 data
}

__global__ __launch_bounds__(256) void hist_k(const int* __restrict__ ei,
                                              const int* __restrict__ flag,
                                              int* __restrict__ cnt) {
  bool is32 = (*flag != 0);
  int stride = gridDim.x * blockDim.x;
  for (int e = blockIdx.x * blockDim.x + threadIdx.x; e < NEDGES; e += stride) {
    int d = is32 ? ei[NEDGES + e] : ei[2 * NEDGES + 2 * e];
    atomicAdd(&cnt[d], 1);
  }
}

// ---- hierarchical exclusive scan of cnt -> rs ----
__global__ __launch_bounds__(256) void scan1_k(const int* __restrict__ cnt,
                                               int* __restrict__ rs,
                                               int* __restrict__ bsum) {
  __shared__ int sm[256];
  int t = threadIdx.x;
  int i = blockIdx.x * 256 + t;
  int v = (i < NNODES) ? cnt[i] : 0;
  sm[t] = v;
  __syncthreads();
  for (int off = 1; off < 256; off <<= 1) {
    int val = (t >= off) ? sm[t - off] : 0;
    __syncthreads();
    sm[t] += val;
    __syncthreads();
  }
  if (i < NNODES) rs[i] = sm[t] - v;
  if (t == 255) bsum[blockIdx.x] = sm[255];
}

__global__ __launch_bounds__(512) void scan2_k(int* __restrict__ bsum, int* __restrict__ rs) {
  __shared__ int sm[512];
  int t = threadIdx.x;
  int v = (t < NB1) ? bsum[t] : 0;
  sm[t] = v;
  __syncthreads();
  for (int off = 1; off < 512; off <<= 1) {
    int val = (t >= off) ? sm[t - off] : 0;
    __syncthreads();
    sm[t] += val;
    __syncthreads();
  }
  if (t < NB1) bsum[t] = sm[t] - v;
  if (t == 511) rs[NNODES] = sm[511];
}

__global__ __launch_bounds__(256) void scan3_k(const int* __restrict__ cnt,
                                               const int* __restrict__ bsum,
                                               int* __restrict__ rs,
                                               float* __restrict__ dinv) {
  int i = blockIdx.x * 256 + threadIdx.x;
  if (i < NNODES) {
    rs[i] += bsum[blockIdx.x];
    dinv[i] = rsqrtf((float)(cnt[i] + 1));
  }
}

__global__ __launch_bounds__(256) void scatter_k(const int* __restrict__ ei,
                                                 const int* __restrict__ flag,
                                                 const int* __restrict__ rs,
                                                 int* __restrict__ cursor,
                                                 int* __restrict__ csrc) {
  bool is32 = (*flag != 0);
  int stride = gridDim.x * blockDim.x;
  for (int e = blockIdx.x * blockDim.x + threadIdx.x; e < NEDGES; e += stride) {
    int s, d;
    if (is32) { s = ei[e];     d = ei[NEDGES + e]; }
    else      { s = ei[2 * e]; d = ei[2 * NEDGES + 2 * e]; }
    int pos = rs[d] + atomicAdd(&cursor[d], 1);
    csrc[pos] = s;
  }
}

// ---- weight transpose+convert ----
__global__ __launch_bounds__(256) void w1t_k(const float* __restrict__ W1, short* __restrict__ W1t) {
  int i = blockIdx.x * 256 + threadIdx.x;
  if (i < NFEAT * NHID) {
    int k = i >> 7, c = i & 127;
    W1t[(size_t)c * NFEAT + k] = f2bf(W1[i]);
  }
}
__global__ __launch_bounds__(256) void w2t_k(const float* __restrict__ W2, short* __restrict__ W2t) {
  int i = blockIdx.x * 256 + threadIdx.x;
  if (i < NHID * NCLS) {
    int k = i >> 6, c = i & 63;
    W2t[(size_t)c * NHID + k] = f2bf(W2[i]);
  }
}

// ---- fused MLP, K-split: block = 16 rows, wave w owns K-slice [w*128,(w+1)*128) ----
__global__ __launch_bounds__(256, 4) void mlp2_k(const float* __restrict__ x,
                                                 const short* __restrict__ W1t,
                                                 const float* __restrict__ b1,
                                                 const short* __restrict__ W2t,
                                                 const float* __restrict__ b2,
                                                 const float* __restrict__ dinv,
                                                 unsigned short* __restrict__ x0,
                                                 unsigned short* __restrict__ g0) {
  __shared__ __align__(16) float part[4][16][134]; // padded: rows shift 6 banks
  int tid = threadIdx.x, lane = tid & 63, wave = tid >> 6;
  int r = lane & 15, q = lane >> 4;
  int row0 = blockIdx.x * 16; // NNODES = 16*6250 exactly
  const float* xr = x + (size_t)(row0 + r) * NFEAT + wave * 128 + q * 8;
  const short* bp1 = W1t + (size_t)r * NFEAT + wave * 128 + q * 8;

  float4 A[4][2];
#pragma unroll
  for (int c = 0; c < 4; ++c) {
    A[c][0] = *reinterpret_cast<const float4*>(xr + c * 32);
    A[c][1] = *reinterpret_cast<const float4*>(xr + c * 32 + 4);
  }
  f4v acc[8];
#pragma unroll
  for (int i = 0; i < 8; ++i) acc[i] = (f4v){0.f, 0.f, 0.f, 0.f};
#pragma unroll
  for (int c = 0; c < 4; ++c) {
    s8v a;
    a[0] = f2bf(A[c][0].x); a[1] = f2bf(A[c][0].y);
    a[2] = f2bf(A[c][0].z); a[3] = f2bf(A[c][0].w);
    a[4] = f2bf(A[c][1].x); a[5] = f2bf(A[c][1].y);
    a[6] = f2bf(A[c][1].z); a[7] = f2bf(A[c][1].w);
#pragma unroll
    for (int ct = 0; ct < 8; ++ct) {
      s8v b = *reinterpret_cast<const s8v*>(bp1 + (size_t)ct * 16 * NFEAT + c * 32);
      acc[ct] = __builtin_amdgcn_mfma_f32_16x16x32_bf16(a, b, acc[ct], 0, 0, 0);
    }
  }
#pragma unroll
  for (int ct = 0; ct < 8; ++ct)
#pragma unroll
    for (int j = 0; j < 4; ++j)
      part[wave][q * 4 + j][ct * 16 + r] = acc[ct][j];
  __syncthreads();

  s8v a2[4];
#pragma unroll
  for (int c2 = 0; c2 < 4; ++c2) {
    int k = c2 * 32 + q * 8;
    float hv[8];
#pragma unroll
    for (int jj = 0; jj < 8; jj += 2) {
      float sx = 0.f, sy = 0.f;
#pragma unroll
      for (int w = 0; w < 4; ++w) {
        float2 p = *reinterpret_cast<const float2*>(&part[w][r][k + jj]);
        sx += p.x; sy += p.y;
      }
      hv[jj] = sx; hv[jj + 1] = sy;
    }
    float4 bb0 = *reinterpret_cast<const float4*>(b1 + k);
    float4 bb1 = *reinterpret_cast<const float4*>(b1 + k + 4);
    hv[0] += bb0.x; hv[1] += bb0.y; hv[2] += bb0.z; hv[3] += bb0.w;
    hv[4] += bb1.x; hv[5] += bb1.y; hv[6] += bb1.z; hv[7] += bb1.w;
#pragma unroll
    for (int i = 0; i < 8; ++i) {
      float v = hv[i] > 0.f ? hv[i] : 0.f;
      a2[c2][i] = f2bf(v);
    }
  }
  const short* bp2 = W2t + (size_t)(wave * 16 + r) * NHID + q * 8;
  f4v acc2 = (f4v){0.f, 0.f, 0.f, 0.f};
#pragma unroll
  for (int c2 = 0; c2 < 4; ++c2) {
    s8v b = *reinterpret_cast<const s8v*>(bp2 + c2 * 32);
    acc2 = __builtin_amdgcn_mfma_f32_16x16x32_bf16(a2[c2], b, acc2, 0, 0, 0);
  }
  float bias2 = b2[wave * 16 + r];
  float dvv[4];
#pragma unroll
  for (int j = 0; j < 4; ++j) dvv[j] = dinv[row0 + q * 4 + j];
  __syncthreads();

  short* pkx = (short*)&part[0][0][0]; // [16][72]
  short* pkg = pkx + 16 * 72;
#pragma unroll
  for (int j = 0; j < 4; ++j) {
    float hh = acc2[j] + bias2;
    int off = (q * 4 + j) * 72 + wave * 16 + r;
    pkx[off] = f2bf(hh);
    pkg[off] = f2bf(dvv[j] * hh);
  }
  __syncthreads();
  int sel = tid >> 7;
  int t2 = tid & 127;
  int rw = t2 >> 3, seg = t2 & 7;
  const short* src = (sel ? pkg : pkx) + rw * 72 + seg * 8;
  s8v v = *reinterpret_cast<const s8v*>(src);
  unsigned short* dst = (sel ? g0 : x0) + (size_t)(row0 + rw) * NCLS + seg * 8;
  *reinterpret_cast<s8v*>(dst) = v;
}

// ---- propagation: 4 nodes/wave, 16 lanes/node, group-uniform predication ----
__global__ __launch_bounds__(256) void prop_k(const unsigned short* __restrict__ gin,
                                              const unsigned short* __restrict__ x0,
                                              const float* __restrict__ dinv,
                                              const int* __restrict__ rs,
                                              const int* __restrict__ csrc,
                                              unsigned short* __restrict__ gout,
                                              float* __restrict__ out,
                                              int last) {
  int tid = threadIdx.x;
  int lane = tid & 63;
  int r = lane & 15;
  int gbase = lane & 48;
  int node = blockIdx.x * 16 + (tid >> 6) * 4 + (lane >> 4); // 6250*16 == NNODES
  int b = rs[node];
  int deg = rs[node + 1] - b;

  uint2 sv = ((const uint2*)(gin + (size_t)node * NCLS))[r];
  float a0 = bflo(sv.x), a1 = bfhi(sv.x), a2 = bflo(sv.y), a3 = bfhi(sv.y);

  int m = deg;
  m = max(m, __shfl_xor(m, 16));
  m = max(m, __shfl_xor(m, 32));

  for (int basek = 0; basek < m; basek += 16) {
    int idx = 0;
    if (basek + r < deg) idx = csrc[b + basek + r];
#pragma unroll
    for (int j = 0; j < 16; ++j) {
      int sj = __shfl(idx, gbase + j);
      if (basek + j < deg) { // uniform within 16-lane group -> exec-masked, no load
        uint2 v = ((const uint2*)(gin + (size_t)sj * NCLS))[r];
        a0 += bflo(v.x); a1 += bfhi(v.x); a2 += bflo(v.y); a3 += bfhi(v.y);
      }
    }
  }

  float dvn = dinv[node];
  uint2 xv = ((const uint2*)(x0 + (size_t)node * NCLS))[r];
  float h0 = 0.9f * (dvn * a0) + 0.1f * bflo(xv.x);
  float h1 = 0.9f * (dvn * a1) + 0.1f * bfhi(xv.x);
  float h2 = 0.9f * (dvn * a2) + 0.1f * bflo(xv.y);
  float h3 = 0.9f * (dvn * a3) + 0.1f * bfhi(xv.y);

  if (!last) {
    unsigned int p0 = (unsigned short)f2bf(dvn * h0) |
                      ((unsigned int)(unsigned short)f2bf(dvn * h1) << 16);
    unsigned int p1 = (unsigned short)f2bf(dvn * h2) |
                      ((unsigned int)(unsigned short)f2bf(dvn * h3) << 16);
    uint2 o; o.x = p0; o.y = p1;
    ((uint2*)(gout + (size_t)node * NCLS))[r] = o;
  } else {
    float mx = fmaxf(fmaxf(h0, h1), fmaxf(h2, h3));
#pragma unroll
    for (int off = 1; off < 16; off <<= 1) mx = fmaxf(mx, __shfl_xor(mx, off));
    float s = __expf(h0 - mx) + __expf(h1 - mx) + __expf(h2 - mx) + __expf(h3 - mx);
#pragma unroll
    for (int off = 1; off < 16; off <<= 1) s += __shfl_xor(s, off);
    float ls = __logf(s);
    float4 o = {h0 - mx - ls, h1 - mx - ls, h2 - mx - ls, h3 - mx - ls};
    *(float4*)(out + (size_t)node * NCLS + r * 4) = o;
  }
}

extern "C" void kernel_launch(void* const* d_in, const int* in_sizes, int n_in,
                              void* d_out, int out_size, void* d_ws, size_t ws_size,
                              hipStream_t stream) {
  const float* x  = (const float*)d_in[0];
  const int*   ei = (const int*)d_in[1];
  const float* W1 = (const float*)d_in[2];
  const float* b1 = (const float*)d_in[3];
  const float* W2 = (const float*)d_in[4];
  const float* b2 = (const float*)d_in[5];

  char* ws = (char*)d_ws;
  unsigned short* x0bf   = (unsigned short*)(ws);             // 12.8 MB
  unsigned short* gA     = (unsigned short*)(ws + 12800000);  // 12.8 MB
  unsigned short* gB     = (unsigned short*)(ws + 25600256);  // 12.8 MB
  int*            csrc   = (int*)(ws + 38400384);             // 6.4 MB
  int*            cnt    = (int*)(ws + 44800384);             // 400 KB
  int*            rs     = (int*)(ws + 45200384);             // 400.128 KB
  int*            cursor = (int*)(ws + 45600512);             // 400 KB
  float*          dinv   = (float*)(ws + 46000512);           // 400 KB
  short*          W1t    = (short*)(ws + 46800512);           // 128 KB
  short*          W2t    = (short*)(ws + 46931584);           // 16 KB
  int*            flag   = (int*)(ws + 46947968);             // 4 B (+pad)
  int*            bsum   = (int*)(ws + 46948096);             // 1.6 KB

  hipMemsetAsync(ws + 44800384, 0, 1200128, stream); // cnt + rs + cursor
  hipMemsetAsync(ws + 46947968, 0, 128, stream);     // flag

  detect_k<<<1, 1024, 0, stream>>>(ei, flag);
  hist_k<<<2048, 256, 0, stream>>>(ei, flag, cnt);
  scan1_k<<<NB1, 256, 0, stream>>>(cnt, rs, bsum);
  scan2_k<<<1, 512, 0, stream>>>(bsum, rs);
  scan3_k<<<NB1, 256, 0, stream>>>(cnt, bsum, rs, dinv);
  scatter_k<<<2048, 256, 0, stream>>>(ei, flag, rs, cursor, csrc);

  w1t_k<<<(NFEAT * NHID + 255) / 256, 256, 0, stream>>>(W1, W1t);
  w2t_k<<<(NHID * NCLS + 255) / 256, 256, 0, stream>>>(W2, W2t);

  mlp2_k<<<NNODES / 16, 256, 0, stream>>>(x, W1t, b1, W2t, b2, dinv, x0bf, gB);

  // g0 in gB; odd t writes gA, even t writes gB; t=10 reads gA, writes d_out (f32)
  for (int t = 1; t <= 10; ++t) {
    const unsigned short* gin = (t & 1) ? gB : gA;
    unsigned short* gout      = (t & 1) ? gA : gB;
    prop_k<<<NNODES / 16, 256, 0, stream>>>(gin, x0bf, dinv, rs, csrc, gout,
                                            (float*)d_out, t == 10);
  }
}

// Round 8
// 669.761 us; speedup vs baseline: 1.6478x; 1.1015x over previous
//
#include <hip/hip_runtime.h>
#include <hip/hip_bf16.h>

typedef __attribute__((ext_vector_type(8))) short s8v;
typedef __attribute__((ext_vector_type(4))) float f4v;

#define NNODES 100000
#define NEDGES 1600000
#define NFEAT 512
#define NHID 128
#define NCLS 64
#define NB1 391   // ceil(NNODES/256)

static __device__ __forceinline__ short f2bf(float f) {
  __hip_bfloat16 h = __float2bfloat16(f);
  return __builtin_bit_cast(short, h);
}
static __device__ __forceinline__ float bflo(unsigned int u) {
  return __builtin_bit_cast(float, u << 16);
}
static __device__ __forceinline__ float bfhi(unsigned int u) {
  return __builtin_bit_cast(float, u & 0xFFFF0000u);
}
static __device__ __forceinline__ void glds16(const void* g, void* l) {
  __builtin_amdgcn_global_load_lds(
      (const __attribute__((address_space(1))) unsigned int*)g,
      (__attribute__((address_space(3))) unsigned int*)l, 16, 0, 0);
}

// ---- edge dtype detection: int64 => odd 32-bit words all zero ----
__global__ __launch_bounds__(1024) void detect_k(const int* __restrict__ ei, int* flag) {
  int i = blockIdx.x * blockDim.x + threadIdx.x;
  if (i < 1024 && ei[2 * i + 1] != 0) atomicOr(flag, 1); // flag=1 -> int32 data
}

__global__ __launch_bounds__(256) void hist_k(const int* __restrict__ ei,
                                              const int* __restrict__ flag,
                                              int* __restrict__ cnt) {
  bool is32 = (*flag != 0);
  int stride = gridDim.x * blockDim.x;
  for (int e = blockIdx.x * blockDim.x + threadIdx.x; e < NEDGES; e += stride) {
    int d = is32 ? ei[NEDGES + e] : ei[2 * NEDGES + 2 * e];
    atomicAdd(&cnt[d], 1);
  }
}

// ---- hierarchical exclusive scan of cnt -> rs ----
__global__ __launch_bounds__(256) void scan1_k(const int* __restrict__ cnt,
                                               int* __restrict__ rs,
                                               int* __restrict__ bsum) {
  __shared__ int sm[256];
  int t = threadIdx.x;
  int i = blockIdx.x * 256 + t;
  int v = (i < NNODES) ? cnt[i] : 0;
  sm[t] = v;
  __syncthreads();
  for (int off = 1; off < 256; off <<= 1) {
    int val = (t >= off) ? sm[t - off] : 0;
    __syncthreads();
    sm[t] += val;
    __syncthreads();
  }
  if (i < NNODES) rs[i] = sm[t] - v;
  if (t == 255) bsum[blockIdx.x] = sm[255];
}

__global__ __launch_bounds__(512) void scan2_k(int* __restrict__ bsum, int* __restrict__ rs) {
  __shared__ int sm[512];
  int t = threadIdx.x;
  int v = (t < NB1) ? bsum[t] : 0;
  sm[t] = v;
  __syncthreads();
  for (int off = 1; off < 512; off <<= 1) {
    int val = (t >= off) ? sm[t - off] : 0;
    __syncthreads();
    sm[t] += val;
    __syncthreads();
  }
  if (t < NB1) bsum[t] = sm[t] - v;
  if (t == 511) rs[NNODES] = sm[511];
}

__global__ __launch_bounds__(256) void scan3_k(const int* __restrict__ cnt,
                                               const int* __restrict__ bsum,
                                               int* __restrict__ rs,
                                               float* __restrict__ dinv) {
  int i = blockIdx.x * 256 + threadIdx.x;
  if (i < NNODES) {
    rs[i] += bsum[blockIdx.x];
    dinv[i] = rsqrtf((float)(cnt[i] + 1));
  }
}

__global__ __launch_bounds__(256) void scatter_k(const int* __restrict__ ei,
                                                 const int* __restrict__ flag,
                                                 const int* __restrict__ rs,
                                                 int* __restrict__ cursor,
                                                 int* __restrict__ csrc) {
  bool is32 = (*flag != 0);
  int stride = gridDim.x * blockDim.x;
  for (int e = blockIdx.x * blockDim.x + threadIdx.x; e < NEDGES; e += stride) {
    int s, d;
    if (is32) { s = ei[e];     d = ei[NEDGES + e]; }
    else      { s = ei[2 * e]; d = ei[2 * NEDGES + 2 * e]; }
    int pos = rs[d] + atomicAdd(&cursor[d], 1);
    csrc[pos] = s;
  }
}

// ---- weight transpose+convert ----
__global__ __launch_bounds__(256) void w1t_k(const float* __restrict__ W1, short* __restrict__ W1t) {
  int i = blockIdx.x * 256 + threadIdx.x;
  if (i < NFEAT * NHID) {
    int k = i >> 7, c = i & 127;
    W1t[(size_t)c * NFEAT + k] = f2bf(W1[i]);
  }
}
__global__ __launch_bounds__(256) void w2t_k(const float* __restrict__ W2, short* __restrict__ W2t) {
  int i = blockIdx.x * 256 + threadIdx.x;
  if (i < NHID * NCLS) {
    int k = i >> 6, c = i & 63;
    W2t[(size_t)c * NHID + k] = f2bf(W2[i]);
  }
}

// ---- fused MLP, m97-style: BM=128, BN=128, BK=64, dbuf LDS for A and B ----
// A: reg-staged coalesced f32 -> bf16 -> swizzled ds_write.  B: glds pre-swizzled.
// Then gemm2 (h1 tile via LDS) + packed coalesced x0/g0 epilogue. 64KB LDS -> 2 blk/CU.
__global__ __launch_bounds__(256, 2) void mlp3_k(const float* __restrict__ x,
                                                 const short* __restrict__ W1t,
                                                 const float* __restrict__ b1,
                                                 const short* __restrict__ W2t,
                                                 const float* __restrict__ b2,
                                                 const float* __restrict__ dinv,
                                                 unsigned short* __restrict__ x0,
                                                 unsigned short* __restrict__ g0) {
  __shared__ __align__(16) short As[2][8192]; // 2 x 128 rows x 64 k bf16 (16KB each)
  __shared__ __align__(16) short Bs[2][8192]; // 2 x 128 col x 64 k bf16
  int tid = threadIdx.x, lane = tid & 63, wave = tid >> 6;
  int r = lane & 15, q = lane >> 4;
  int G = tid >> 4, li = tid & 15;
  int row0 = blockIdx.x * 128;
  int wr = (wave >> 1) * 64, wc = (wave & 1) * 64;
  char* AsB = (char*)As;
  char* BsB = (char*)Bs;

  // ---- staging helpers (inlined) ----
  // A rows for this thread: row = rd*16 + G, 16B at float col li*4 within 64-chunk
  auto loadA = [&](float4* av, int kk) {
#pragma unroll
    for (int rd = 0; rd < 8; ++rd) {
      int row = rd * 16 + G;
      int grow = row0 + row; if (grow >= NNODES) grow = NNODES - 1;
      av[rd] = *reinterpret_cast<const float4*>(x + (size_t)grow * NFEAT + kk + li * 4);
    }
  };
  auto writeA = [&](const float4* av, int buf) {
#pragma unroll
    for (int rd = 0; rd < 8; ++rd) {
      int row = rd * 16 + G;
      uint2 u;
      u.x = (unsigned int)(unsigned short)f2bf(av[rd].x) |
            ((unsigned int)(unsigned short)f2bf(av[rd].y) << 16);
      u.y = (unsigned int)(unsigned short)f2bf(av[rd].z) |
            ((unsigned int)(unsigned short)f2bf(av[rd].w) << 16);
      *(uint2*)(AsB + buf * 16384 + row * 128 + (((li >> 1) ^ (row & 7)) << 4) + (li & 1) * 8) = u;
    }
  };
  auto stageB = [&](int buf, int kk) {
#pragma unroll
    for (int i2 = 0; i2 < 4; ++i2) {
      int i = wave * 4 + i2;
      int col = i * 8 + (lane >> 3);
      int srcg = (lane & 7) ^ (col & 7);
      glds16(W1t + (size_t)col * NFEAT + kk + srcg * 8, BsB + buf * 16384 + i * 1024);
    }
  };

  f4v acc[4][4];
#pragma unroll
  for (int a = 0; a < 4; ++a)
#pragma unroll
    for (int b = 0; b < 4; ++b) acc[a][b] = (f4v){0.f, 0.f, 0.f, 0.f};

  // prologue: stage iter 0
  {
    float4 av[8];
    loadA(av, 0);
    stageB(0, 0);
    writeA(av, 0);
  }
  __syncthreads();

  int cur = 0;
  for (int c = 0; c < 8; ++c) {
    float4 av[8];
    if (c < 7) {               // issue next-tile loads early (T14)
      loadA(av, (c + 1) * 64);
      stageB(cur ^ 1, (c + 1) * 64);
    }
#pragma unroll
    for (int kc = 0; kc < 2; ++kc) {
      s8v af[4], bfr[4];
#pragma unroll
      for (int rt = 0; rt < 4; ++rt) {
        int arow = wr + rt * 16 + r;
        af[rt] = *(const s8v*)(AsB + cur * 16384 + arow * 128 +
                               (((kc * 4 + q) ^ (arow & 7)) << 4));
      }
#pragma unroll
      for (int ct = 0; ct < 4; ++ct) {
        int bcol = wc + ct * 16 + r;
        bfr[ct] = *(const s8v*)(BsB + cur * 16384 + bcol * 128 +
                                (((kc * 4 + q) ^ (bcol & 7)) << 4));
      }
#pragma unroll
      for (int rt = 0; rt < 4; ++rt)
#pragma unroll
        for (int ct = 0; ct < 4; ++ct)
          acc[rt][ct] = __builtin_amdgcn_mfma_f32_16x16x32_bf16(af[rt], bfr[ct], acc[rt][ct], 0, 0, 0);
    }
    if (c < 7) writeA(av, cur ^ 1);  // write-late (after vmcnt on av)
    __syncthreads();
    cur ^= 1;
  }

  // ---- h1 tile (relu, bf16) -> LDS over As (both buffers), swizzled 256B rows ----
  {
    float bias1[4];
#pragma unroll
    for (int ct = 0; ct < 4; ++ct) bias1[ct] = b1[wc + ct * 16 + r];
#pragma unroll
    for (int rt = 0; rt < 4; ++rt)
#pragma unroll
      for (int ct = 0; ct < 4; ++ct) {
        int col = wc + ct * 16 + r;
#pragma unroll
        for (int j = 0; j < 4; ++j) {
          int row = wr + rt * 16 + q * 4 + j;
          float v = acc[rt][ct][j] + bias1[ct];
          v = v > 0.f ? v : 0.f;
          *(short*)(AsB + row * 256 + (((col >> 3) ^ (row & 15)) << 4) + (col & 7) * 2) = f2bf(v);
        }
      }
  }
  __syncthreads();

  // ---- gemm2: h1[128x128] @ W2t -> acc2[128x64]; wave covers 64 rows x 32 cols ----
  int wc2 = (wave & 1) * 32;
  f4v acc2[4][2];
#pragma unroll
  for (int a = 0; a < 4; ++a)
#pragma unroll
    for (int b = 0; b < 2; ++b) acc2[a][b] = (f4v){0.f, 0.f, 0.f, 0.f};
#pragma unroll
  for (int kc = 0; kc < 4; ++kc) {
    s8v a2[4], b2f[2];
#pragma unroll
    for (int rt = 0; rt < 4; ++rt) {
      int row = wr + rt * 16 + r;
      a2[rt] = *(const s8v*)(AsB + row * 256 + (((kc * 4 + q) ^ (row & 15)) << 4));
    }
#pragma unroll
    for (int ct = 0; ct < 2; ++ct) {
      int col2 = wc2 + ct * 16 + r;
      b2f[ct] = *(const s8v*)(W2t + (size_t)col2 * NHID + kc * 32 + q * 8);
    }
#pragma unroll
    for (int rt = 0; rt < 4; ++rt)
#pragma unroll
      for (int ct = 0; ct < 2; ++ct)
        acc2[rt][ct] = __builtin_amdgcn_mfma_f32_16x16x32_bf16(a2[rt], b2f[ct], acc2[rt][ct], 0, 0, 0);
  }

  // ---- epilogue: pack x0/g0 into Bs (swizzled 128B rows), then coalesced stores ----
  {
    float bias2[2];
#pragma unroll
    for (int ct = 0; ct < 2; ++ct) bias2[ct] = b2[wc2 + ct * 16 + r];
#pragma unroll
    for (int rt = 0; rt < 4; ++rt)
#pragma unroll
      for (int j = 0; j < 4; ++j) {
        int row = wr + rt * 16 + q * 4 + j;
        int grow = row0 + row;
        float dv = dinv[grow < NNODES ? grow : NNODES - 1];
#pragma unroll
        for (int ct = 0; ct < 2; ++ct) {
          float hh = acc2[rt][ct][j] + bias2[ct];
          int col = wc2 + ct * 16 + r;
          int byte = row * 128 + (((col >> 3) ^ (row & 7)) << 4) + (col & 7) * 2;
          *(short*)(BsB + byte) = f2bf(hh);
          *(short*)(BsB + 16384 + byte) = f2bf(dv * hh);
        }
      }
  }
  __syncthreads();
#pragma unroll
  for (int rd = 0; rd < 8; ++rd) {
    int row = rd * 16 + G;
    int grow = row0 + row;
    if (grow < NNODES) {
      int byte = row * 128 + (((li >> 1) ^ (row & 7)) << 4) + (li & 1) * 8;
      uint2 vx = *(const uint2*)(BsB + byte);
      uint2 vg = *(const uint2*)(BsB + 16384 + byte);
      *(uint2*)(x0 + (size_t)grow * NCLS + li * 4) = vx;
      *(uint2*)(g0 + (size_t)grow * NCLS + li * 4) = vg;
    }
  }
}

// ---- propagation: 4 nodes/wave, 16 lanes/node, group-uniform predication ----
__global__ __launch_bounds__(256) void prop_k(const unsigned short* __restrict__ gin,
                                              const unsigned short* __restrict__ x0,
                                              const float* __restrict__ dinv,
                                              const int* __restrict__ rs,
                                              const int* __restrict__ csrc,
                                              unsigned short* __restrict__ gout,
                                              float* __restrict__ out,
                                              int last) {
  int tid = threadIdx.x;
  int lane = tid & 63;
  int r = lane & 15;
  int gbase = lane & 48;
  int node = blockIdx.x * 16 + (tid >> 6) * 4 + (lane >> 4); // 6250*16 == NNODES
  int b = rs[node];
  int deg = rs[node + 1] - b;

  uint2 sv = ((const uint2*)(gin + (size_t)node * NCLS))[r];
  float a0 = bflo(sv.x), a1 = bfhi(sv.x), a2 = bflo(sv.y), a3 = bfhi(sv.y);

  int m = deg;
  m = max(m, __shfl_xor(m, 16));
  m = max(m, __shfl_xor(m, 32));

  for (int basek = 0; basek < m; basek += 16) {
    int idx = 0;
    if (basek + r < deg) idx = csrc[b + basek + r];
#pragma unroll
    for (int j = 0; j < 16; ++j) {
      int sj = __shfl(idx, gbase + j);
      if (basek + j < deg) { // uniform within 16-lane group -> exec-masked, no load
        uint2 v = ((const uint2*)(gin + (size_t)sj * NCLS))[r];
        a0 += bflo(v.x); a1 += bfhi(v.x); a2 += bflo(v.y); a3 += bfhi(v.y);
      }
    }
  }

  float dvn = dinv[node];
  uint2 xv = ((const uint2*)(x0 + (size_t)node * NCLS))[r];
  float h0 = 0.9f * (dvn * a0) + 0.1f * bflo(xv.x);
  float h1 = 0.9f * (dvn * a1) + 0.1f * bfhi(xv.x);
  float h2 = 0.9f * (dvn * a2) + 0.1f * bflo(xv.y);
  float h3 = 0.9f * (dvn * a3) + 0.1f * bfhi(xv.y);

  if (!last) {
    unsigned int p0 = (unsigned short)f2bf(dvn * h0) |
                      ((unsigned int)(unsigned short)f2bf(dvn * h1) << 16);
    unsigned int p1 = (unsigned short)f2bf(dvn * h2) |
                      ((unsigned int)(unsigned short)f2bf(dvn * h3) << 16);
    uint2 o; o.x = p0; o.y = p1;
    ((uint2*)(gout + (size_t)node * NCLS))[r] = o;
  } else {
    float mx = fmaxf(fmaxf(h0, h1), fmaxf(h2, h3));
#pragma unroll
    for (int off = 1; off < 16; off <<= 1) mx = fmaxf(mx, __shfl_xor(mx, off));
    float s = __expf(h0 - mx) + __expf(h1 - mx) + __expf(h2 - mx) + __expf(h3 - mx);
#pragma unroll
    for (int off = 1; off < 16; off <<= 1) s += __shfl_xor(s, off);
    float ls = __logf(s);
    float4 o = {h0 - mx - ls, h1 - mx - ls, h2 - mx - ls, h3 - mx - ls};
    *(float4*)(out + (size_t)node * NCLS + r * 4) = o;
  }
}

extern "C" void kernel_launch(void* const* d_in, const int* in_sizes, int n_in,
                              void* d_out, int out_size, void* d_ws, size_t ws_size,
                              hipStream_t stream) {
  const float* x  = (const float*)d_in[0];
  const int*   ei = (const int*)d_in[1];
  const float* W1 = (const float*)d_in[2];
  const float* b1 = (const float*)d_in[3];
  const float* W2 = (const float*)d_in[4];
  const float* b2 = (const float*)d_in[5];

  char* ws = (char*)d_ws;
  unsigned short* x0bf   = (unsigned short*)(ws);             // 12.8 MB
  unsigned short* gA     = (unsigned short*)(ws + 12800000);  // 12.8 MB
  unsigned short* gB     = (unsigned short*)(ws + 25600256);  // 12.8 MB
  int*            csrc   = (int*)(ws + 38400384);             // 6.4 MB
  int*            cnt    = (int*)(ws + 44800384);             // 400 KB
  int*            rs     = (int*)(ws + 45200384);             // 400.128 KB
  int*            cursor = (int*)(ws + 45600512);             // 400 KB
  float*          dinv   = (float*)(ws + 46000512);           // 400 KB
  short*          W1t    = (short*)(ws + 46800512);           // 128 KB
  short*          W2t    = (short*)(ws + 46931584);           // 16 KB
  int*            flag   = (int*)(ws + 46947968);             // 4 B (+pad)
  int*            bsum   = (int*)(ws + 46948096);             // 1.6 KB

  hipMemsetAsync(ws + 44800384, 0, 1200128, stream); // cnt + rs + cursor
  hipMemsetAsync(ws + 46947968, 0, 128, stream);     // flag

  detect_k<<<1, 1024, 0, stream>>>(ei, flag);
  hist_k<<<2048, 256, 0, stream>>>(ei, flag, cnt);
  scan1_k<<<NB1, 256, 0, stream>>>(cnt, rs, bsum);
  scan2_k<<<1, 512, 0, stream>>>(bsum, rs);
  scan3_k<<<NB1, 256, 0, stream>>>(cnt, bsum, rs, dinv);
  scatter_k<<<2048, 256, 0, stream>>>(ei, flag, rs, cursor, csrc);

  w1t_k<<<(NFEAT * NHID + 255) / 256, 256, 0, stream>>>(W1, W1t);
  w2t_k<<<(NHID * NCLS + 255) / 256, 256, 0, stream>>>(W2, W2t);

  mlp3_k<<<(NNODES + 127) / 128, 256, 0, stream>>>(x, W1t, b1, W2t, b2, dinv, x0bf, gB);

  // g0 in gB; odd t writes gA, even t writes gB; t=10 reads gA, writes d_out (f32)
  for (int t = 1; t <= 10; ++t) {
    const unsigned short* gin = (t & 1) ? gB : gA;
    unsigned short* gout      = (t & 1) ? gA : gB;
    prop_k<<<NNODES / 16, 256, 0, stream>>>(gin, x0bf, dinv, rs, csrc, gout,
                                            (float*)d_out, t == 10);
  }
}

// Round 9
// 527.541 us; speedup vs baseline: 2.0921x; 1.2696x over previous
//
#include <hip/hip_runtime.h>
#include <hip/hip_bf16.h>

typedef __attribute__((ext_vector_type(8))) short s8v;
typedef __attribute__((ext_vector_type(4))) float f4v;

#define NNODES 100000
#define NEDGES 1600000
#define NFEAT 512
#define NHID 128
#define NCLS 64
#define NB1 391   // ceil(NNODES/256)

static __device__ __forceinline__ short f2bf(float f) {
  __hip_bfloat16 h = __float2bfloat16(f);
  return __builtin_bit_cast(short, h);
}
static __device__ __forceinline__ float bflo(unsigned int u) {
  return __builtin_bit_cast(float, u << 16);
}
static __device__ __forceinline__ float bfhi(unsigned int u) {
  return __builtin_bit_cast(float, u & 0xFFFF0000u);
}
static __device__ __forceinline__ unsigned int pk(float lo, float hi) {
  return (unsigned int)(unsigned short)f2bf(lo) |
         ((unsigned int)(unsigned short)f2bf(hi) << 16);
}
static __device__ __forceinline__ void glds16(const void* g, void* l) {
  __builtin_amdgcn_global_load_lds(
      (const __attribute__((address_space(1))) unsigned int*)g,
      (__attribute__((address_space(3))) unsigned int*)l, 16, 0, 0);
}

// ---- edge dtype detection: int64 => odd 32-bit words all zero ----
__global__ __launch_bounds__(1024) void detect_k(const int* __restrict__ ei, int* flag) {
  int i = blockIdx.x * blockDim.x + threadIdx.x;
  if (i < 1024 && ei[2 * i + 1] != 0) atomicOr(flag, 1); // flag=1 -> int32 data
}

__global__ __launch_bounds__(256) void hist_k(const int* __restrict__ ei,
                                              const int* __restrict__ flag,
                                              int* __restrict__ cnt) {
  bool is32 = (*flag != 0);
  int stride = gridDim.x * blockDim.x;
  for (int e = blockIdx.x * blockDim.x + threadIdx.x; e < NEDGES; e += stride) {
    int d = is32 ? ei[NEDGES + e] : ei[2 * NEDGES + 2 * e];
    atomicAdd(&cnt[d], 1);
  }
}

// ---- hierarchical exclusive scan of cnt -> rs ----
__global__ __launch_bounds__(256) void scan1_k(const int* __restrict__ cnt,
                                               int* __restrict__ rs,
                                               int* __restrict__ bsum) {
  __shared__ int sm[256];
  int t = threadIdx.x;
  int i = blockIdx.x * 256 + t;
  int v = (i < NNODES) ? cnt[i] : 0;
  sm[t] = v;
  __syncthreads();
  for (int off = 1; off < 256; off <<= 1) {
    int val = (t >= off) ? sm[t - off] : 0;
    __syncthreads();
    sm[t] += val;
    __syncthreads();
  }
  if (i < NNODES) rs[i] = sm[t] - v;
  if (t == 255) bsum[blockIdx.x] = sm[255];
}

__global__ __launch_bounds__(512) void scan2_k(int* __restrict__ bsum, int* __restrict__ rs) {
  __shared__ int sm[512];
  int t = threadIdx.x;
  int v = (t < NB1) ? bsum[t] : 0;
  sm[t] = v;
  __syncthreads();
  for (int off = 1; off < 512; off <<= 1) {
    int val = (t >= off) ? sm[t - off] : 0;
    __syncthreads();
    sm[t] += val;
    __syncthreads();
  }
  if (t < NB1) bsum[t] = sm[t] - v;
  if (t == 511) rs[NNODES] = sm[511];
}

__global__ __launch_bounds__(256) void scan3_k(const int* __restrict__ cnt,
                                               const int* __restrict__ bsum,
                                               int* __restrict__ rs,
                                               float* __restrict__ dinv) {
  int i = blockIdx.x * 256 + threadIdx.x;
  if (i < NNODES) {
    rs[i] += bsum[blockIdx.x];
    dinv[i] = rsqrtf((float)(cnt[i] + 1));
  }
}

__global__ __launch_bounds__(256) void scatter_k(const int* __restrict__ ei,
                                                 const int* __restrict__ flag,
                                                 const int* __restrict__ rs,
                                                 int* __restrict__ cursor,
                                                 int* __restrict__ csrc) {
  bool is32 = (*flag != 0);
  int stride = gridDim.x * blockDim.x;
  for (int e = blockIdx.x * blockDim.x + threadIdx.x; e < NEDGES; e += stride) {
    int s, d;
    if (is32) { s = ei[e];     d = ei[NEDGES + e]; }
    else      { s = ei[2 * e]; d = ei[2 * NEDGES + 2 * e]; }
    int pos = rs[d] + atomicAdd(&cursor[d], 1);
    csrc[pos] = s;
  }
}

// ---- weight transpose+convert ----
__global__ __launch_bounds__(256) void w1t_k(const float* __restrict__ W1, short* __restrict__ W1t) {
  int i = blockIdx.x * 256 + threadIdx.x;
  if (i < NFEAT * NHID) {
    int k = i >> 7, c = i & 127;
    W1t[(size_t)c * NFEAT + k] = f2bf(W1[i]);
  }
}
__global__ __launch_bounds__(256) void w2t_k(const float* __restrict__ W2, short* __restrict__ W2t) {
  int i = blockIdx.x * 256 + threadIdx.x;
  if (i < NHID * NCLS) {
    int k = i >> 6, c = i & 63;
    W2t[(size_t)c * NHID + k] = f2bf(W2[i]);
  }
}

// ---- fused MLP: BM=128, BK=64, 512 threads (8 waves), dbuf LDS A+B ----
__global__ __launch_bounds__(512, 4) void mlp3_k(const float* __restrict__ x,
                                                 const short* __restrict__ W1t,
                                                 const float* __restrict__ b1,
                                                 const short* __restrict__ W2t,
                                                 const float* __restrict__ b2,
                                                 const float* __restrict__ dinv,
                                                 unsigned short* __restrict__ x0,
                                                 unsigned short* __restrict__ g0) {
  __shared__ __align__(16) short As[2][8192]; // 2 x 128 rows x 64 k bf16
  __shared__ __align__(16) short Bs[2][8192]; // 2 x 128 col x 64 k bf16
  int tid = threadIdx.x, lane = tid & 63, wave = tid >> 6;
  int r = lane & 15, q = lane >> 4;
  int G = tid >> 4, li = tid & 15;        // A-staging: 32 row-groups x 16
  int row0 = blockIdx.x * 128;
  int wr = (wave >> 1) * 32, wc = (wave & 1) * 64;
  char* AsB = (char*)As;
  char* BsB = (char*)Bs;

  auto loadA = [&](float4* av, int kk) {
#pragma unroll
    for (int rd = 0; rd < 4; ++rd) {
      int row = rd * 32 + G;
      int grow = row0 + row; if (grow >= NNODES) grow = NNODES - 1;
      av[rd] = *reinterpret_cast<const float4*>(x + (size_t)grow * NFEAT + kk + li * 4);
    }
  };
  auto writeA = [&](const float4* av, int buf) {
#pragma unroll
    for (int rd = 0; rd < 4; ++rd) {
      int row = rd * 32 + G;
      uint2 u;
      u.x = pk(av[rd].x, av[rd].y);
      u.y = pk(av[rd].z, av[rd].w);
      *(uint2*)(AsB + buf * 16384 + row * 128 + (((li >> 1) ^ (row & 7)) << 4) + (li & 1) * 8) = u;
    }
  };
  auto stageB = [&](int buf, int kk) {
#pragma unroll
    for (int i2 = 0; i2 < 2; ++i2) {
      int i = wave * 2 + i2;
      int col = i * 8 + (lane >> 3);
      int srcg = (lane & 7) ^ (col & 7);
      glds16(W1t + (size_t)col * NFEAT + kk + srcg * 8, BsB + buf * 16384 + i * 1024);
    }
  };

  f4v acc[2][4];
#pragma unroll
  for (int a = 0; a < 2; ++a)
#pragma unroll
    for (int b = 0; b < 4; ++b) acc[a][b] = (f4v){0.f, 0.f, 0.f, 0.f};

  {
    float4 av[4];
    loadA(av, 0);
    stageB(0, 0);
    writeA(av, 0);
  }
  __syncthreads();

  int cur = 0;
  for (int c = 0; c < 8; ++c) {
    float4 av[4];
    if (c < 7) {               // issue next-tile loads early (T14)
      loadA(av, (c + 1) * 64);
      stageB(cur ^ 1, (c + 1) * 64);
    }
#pragma unroll
    for (int kc = 0; kc < 2; ++kc) {
      s8v af[2], bfr[4];
#pragma unroll
      for (int rt = 0; rt < 2; ++rt) {
        int arow = wr + rt * 16 + r;
        af[rt] = *(const s8v*)(AsB + cur * 16384 + arow * 128 +
                               (((kc * 4 + q) ^ (arow & 7)) << 4));
      }
#pragma unroll
      for (int ct = 0; ct < 4; ++ct) {
        int bcol = wc + ct * 16 + r;
        bfr[ct] = *(const s8v*)(BsB + cur * 16384 + bcol * 128 +
                                (((kc * 4 + q) ^ (bcol & 7)) << 4));
      }
#pragma unroll
      for (int rt = 0; rt < 2; ++rt)
#pragma unroll
        for (int ct = 0; ct < 4; ++ct)
          acc[rt][ct] = __builtin_amdgcn_mfma_f32_16x16x32_bf16(af[rt], bfr[ct], acc[rt][ct], 0, 0, 0);
    }
    if (c < 7) writeA(av, cur ^ 1);  // write-late
    __syncthreads();
    cur ^= 1;
  }

  // ---- h1 tile (relu, bf16) -> LDS (256B swizzled rows over As) ----
  {
    float bias1[4];
#pragma unroll
    for (int ct = 0; ct < 4; ++ct) bias1[ct] = b1[wc + ct * 16 + r];
#pragma unroll
    for (int rt = 0; rt < 2; ++rt)
#pragma unroll
      for (int ct = 0; ct < 4; ++ct) {
        int col = wc + ct * 16 + r;
#pragma unroll
        for (int j = 0; j < 4; ++j) {
          int row = wr + rt * 16 + q * 4 + j;
          float v = acc[rt][ct][j] + bias1[ct];
          v = v > 0.f ? v : 0.f;
          *(short*)(AsB + row * 256 + (((col >> 3) ^ (row & 15)) << 4) + (col & 7) * 2) = f2bf(v);
        }
      }
  }
  __syncthreads();

  // ---- gemm2: h1[128x128] @ W2t; wave: 32 rows x 32 cols ----
  int wc2 = (wave & 1) * 32;
  f4v acc2[2][2];
#pragma unroll
  for (int a = 0; a < 2; ++a)
#pragma unroll
    for (int b = 0; b < 2; ++b) acc2[a][b] = (f4v){0.f, 0.f, 0.f, 0.f};
#pragma unroll
  for (int kc = 0; kc < 4; ++kc) {
    s8v a2[2], b2f[2];
#pragma unroll
    for (int rt = 0; rt < 2; ++rt) {
      int row = wr + rt * 16 + r;
      a2[rt] = *(const s8v*)(AsB + row * 256 + (((kc * 4 + q) ^ (row & 15)) << 4));
    }
#pragma unroll
    for (int ct = 0; ct < 2; ++ct) {
      int col2 = wc2 + ct * 16 + r;
      b2f[ct] = *(const s8v*)(W2t + (size_t)col2 * NHID + kc * 32 + q * 8);
    }
#pragma unroll
    for (int rt = 0; rt < 2; ++rt)
#pragma unroll
      for (int ct = 0; ct < 2; ++ct)
        acc2[rt][ct] = __builtin_amdgcn_mfma_f32_16x16x32_bf16(a2[rt], b2f[ct], acc2[rt][ct], 0, 0, 0);
  }

  // ---- epilogue: pack x0/g0 into Bs (swizzled 128B rows), coalesced stores ----
  {
    float bias2[2];
#pragma unroll
    for (int ct = 0; ct < 2; ++ct) bias2[ct] = b2[wc2 + ct * 16 + r];
#pragma unroll
    for (int rt = 0; rt < 2; ++rt)
#pragma unroll
      for (int j = 0; j < 4; ++j) {
        int row = wr + rt * 16 + q * 4 + j;
        int grow = row0 + row;
        float dv = dinv[grow < NNODES ? grow : NNODES - 1];
#pragma unroll
        for (int ct = 0; ct < 2; ++ct) {
          float hh = acc2[rt][ct][j] + bias2[ct];
          int col = wc2 + ct * 16 + r;
          int byte = row * 128 + (((col >> 3) ^ (row & 7)) << 4) + (col & 7) * 2;
          *(short*)(BsB + byte) = f2bf(hh);
          *(short*)(BsB + 16384 + byte) = f2bf(dv * hh);
        }
      }
  }
  __syncthreads();
#pragma unroll
  for (int rd = 0; rd < 4; ++rd) {
    int row = rd * 32 + G;
    int grow = row0 + row;
    if (grow < NNODES) {
      int byte = row * 128 + (((li >> 1) ^ (row & 7)) << 4) + (li & 1) * 8;
      uint2 vx = *(const uint2*)(BsB + byte);
      uint2 vg = *(const uint2*)(BsB + 16384 + byte);
      *(uint2*)(x0 + (size_t)grow * NCLS + li * 4) = vx;
      *(uint2*)(g0 + (size_t)grow * NCLS + li * 4) = vg;
    }
  }
}

// ---- propagation: 8 nodes/wave, 8 lanes/node, uint4 (16B) gathers, null-row pad ----
__global__ __launch_bounds__(256) void prop_k(const unsigned short* __restrict__ gin,
                                              const unsigned short* __restrict__ x0,
                                              const float* __restrict__ dinv,
                                              const int* __restrict__ rs,
                                              const int* __restrict__ csrc,
                                              unsigned short* __restrict__ gout,
                                              float* __restrict__ out,
                                              int last) {
  int tid = threadIdx.x;
  int lane = tid & 63;
  int r = lane & 7;        // 8 lanes per node
  int gbase = lane & 56;
  int node = blockIdx.x * 32 + (tid >> 6) * 8 + (lane >> 3); // 3125*32 == NNODES
  int b = rs[node];
  int deg = rs[node + 1] - b;

  uint4 sv = ((const uint4*)(gin + (size_t)node * NCLS))[r];
  float a0 = bflo(sv.x), a1 = bfhi(sv.x), a2 = bflo(sv.y), a3 = bfhi(sv.y);
  float a4 = bflo(sv.z), a5 = bfhi(sv.z), a6 = bflo(sv.w), a7 = bfhi(sv.w);

  int m = deg;  // wave-uniform max
  m = max(m, __shfl_xor(m, 8));
  m = max(m, __shfl_xor(m, 16));
  m = max(m, __shfl_xor(m, 32));

  for (int basek = 0; basek < m; basek += 8) {
    int idx = NNODES;  // null row (zeroed)
    if (basek + r < deg) idx = csrc[b + basek + r];
#pragma unroll
    for (int j = 0; j < 8; ++j) {
      int sj = __shfl(idx, gbase + j);
      uint4 v = ((const uint4*)(gin + (size_t)sj * NCLS))[r];
      a0 += bflo(v.x); a1 += bfhi(v.x); a2 += bflo(v.y); a3 += bfhi(v.y);
      a4 += bflo(v.z); a5 += bfhi(v.z); a6 += bflo(v.w); a7 += bfhi(v.w);
    }
  }

  float dvn = dinv[node];
  uint4 xv = ((const uint4*)(x0 + (size_t)node * NCLS))[r];
  float h0 = 0.9f * (dvn * a0) + 0.1f * bflo(xv.x);
  float h1 = 0.9f * (dvn * a1) + 0.1f * bfhi(xv.x);
  float h2 = 0.9f * (dvn * a2) + 0.1f * bflo(xv.y);
  float h3 = 0.9f * (dvn * a3) + 0.1f * bfhi(xv.y);
  float h4 = 0.9f * (dvn * a4) + 0.1f * bflo(xv.z);
  float h5 = 0.9f * (dvn * a5) + 0.1f * bfhi(xv.z);
  float h6 = 0.9f * (dvn * a6) + 0.1f * bflo(xv.w);
  float h7 = 0.9f * (dvn * a7) + 0.1f * bfhi(xv.w);

  if (!last) {
    uint4 o;
    o.x = pk(dvn * h0, dvn * h1);
    o.y = pk(dvn * h2, dvn * h3);
    o.z = pk(dvn * h4, dvn * h5);
    o.w = pk(dvn * h6, dvn * h7);
    ((uint4*)(gout + (size_t)node * NCLS))[r] = o;
  } else {
    float mx = fmaxf(fmaxf(fmaxf(h0, h1), fmaxf(h2, h3)),
                     fmaxf(fmaxf(h4, h5), fmaxf(h6, h7)));
#pragma unroll
    for (int off = 1; off < 8; off <<= 1) mx = fmaxf(mx, __shfl_xor(mx, off));
    float s = __expf(h0 - mx) + __expf(h1 - mx) + __expf(h2 - mx) + __expf(h3 - mx) +
              __expf(h4 - mx) + __expf(h5 - mx) + __expf(h6 - mx) + __expf(h7 - mx);
#pragma unroll
    for (int off = 1; off < 8; off <<= 1) s += __shfl_xor(s, off);
    float ls = __logf(s);
    float* op = out + (size_t)node * NCLS + r * 8;
    float4 o0 = {h0 - mx - ls, h1 - mx - ls, h2 - mx - ls, h3 - mx - ls};
    float4 o1 = {h4 - mx - ls, h5 - mx - ls, h6 - mx - ls, h7 - mx - ls};
    *(float4*)(op) = o0;
    *(float4*)(op + 4) = o1;
  }
}

extern "C" void kernel_launch(void* const* d_in, const int* in_sizes, int n_in,
                              void* d_out, int out_size, void* d_ws, size_t ws_size,
                              hipStream_t stream) {
  const float* x  = (const float*)d_in[0];
  const int*   ei = (const int*)d_in[1];
  const float* W1 = (const float*)d_in[2];
  const float* b1 = (const float*)d_in[3];
  const float* W2 = (const float*)d_in[4];
  const float* b2 = (const float*)d_in[5];

  char* ws = (char*)d_ws;
  unsigned short* x0bf   = (unsigned short*)(ws);             // 12.8 MB
  unsigned short* gA     = (unsigned short*)(ws + 12800000);  // 12.8 MB + null row
  unsigned short* gB     = (unsigned short*)(ws + 25600256);  // 12.8 MB + null row
  int*            csrc   = (int*)(ws + 38400384);             // 6.4 MB
  int*            cnt    = (int*)(ws + 44800384);             // 400 KB
  int*            rs     = (int*)(ws + 45200384);             // 400.128 KB
  int*            cursor = (int*)(ws + 45600512);             // 400 KB
  float*          dinv   = (float*)(ws + 46000512);           // 400 KB
  short*          W1t    = (short*)(ws + 46800512);           // 128 KB
  short*          W2t    = (short*)(ws + 46931584);           // 16 KB
  int*            flag   = (int*)(ws + 46947968);             // 4 B (+pad)
  int*            bsum   = (int*)(ws + 46948096);             // 1.6 KB

  hipMemsetAsync(ws + 44800384, 0, 1200128, stream); // cnt + rs + cursor
  hipMemsetAsync(ws + 46947968, 0, 128, stream);     // flag
  // zero null-gather row (index NNODES) in both state buffers
  hipMemsetAsync((char*)gA + (size_t)NNODES * NCLS * 2, 0, 128, stream);
  hipMemsetAsync((char*)gB + (size_t)NNODES * NCLS * 2, 0, 128, stream);

  detect_k<<<1, 1024, 0, stream>>>(ei, flag);
  hist_k<<<2048, 256, 0, stream>>>(ei, flag, cnt);
  scan1_k<<<NB1, 256, 0, stream>>>(cnt, rs, bsum);
  scan2_k<<<1, 512, 0, stream>>>(bsum, rs);
  scan3_k<<<NB1, 256, 0, stream>>>(cnt, bsum, rs, dinv);
  scatter_k<<<2048, 256, 0, stream>>>(ei, flag, rs, cursor, csrc);

  w1t_k<<<(NFEAT * NHID + 255) / 256, 256, 0, stream>>>(W1, W1t);
  w2t_k<<<(NHID * NCLS + 255) / 256, 256, 0, stream>>>(W2, W2t);

  mlp3_k<<<(NNODES + 127) / 128, 512, 0, stream>>>(x, W1t, b1, W2t, b2, dinv, x0bf, gB);

  // g0 in gB; odd t writes gA, even t writes gB; t=10 reads gA, writes d_out (f32)
  for (int t = 1; t <= 10; ++t) {
    const unsigned short* gin = (t & 1) ? gB : gA;
    unsigned short* gout      = (t & 1) ? gA : gB;
    prop_k<<<NNODES / 32, 256, 0, stream>>>(gin, x0bf, dinv, rs, csrc, gout,
                                            (float*)d_out, t == 10);
  }
}